// Round 2
// baseline (1469.184 us; speedup 1.0000x reference)
//
#include <hip/hip_runtime.h>

#define N_ROWS 65536
#define K_CODES 8192
#define DIM 256
#define CAP 56

// d_out layout (floats): [quantized_st 65536*256][loss 1][indices 65536]
#define LOSS_OFF (N_ROWS * DIM)
#define IDX_OFF (LOSS_OFF + 1)
// scratch inside d_out's quantized region (consumed before gather overwrites):
#define OUT_WBF_U16 0              // W_bf: 8192*256 u16  (4 MB)
#define OUT_ZBF_U16 2097152        // z_bf: 65536*256 u16 (32 MB)
#define OUT_CAND_F 9437184         // cand: 65536*56 uint2 (29.36 MB); ends exactly at 16777216

// d_ws layout (4-byte units), ~1.85 MB total
#define WS_LOSS 0
#define WS_ZNORM 64
#define WS_WNORM (WS_ZNORM + N_ROWS)
#define WS_MARGIN (WS_WNORM + K_CODES)
#define WS_CUT0 (WS_MARGIN + N_ROWS)
#define WS_CNT (WS_CUT0 + N_ROWS)       // uint
#define WS_OVF (WS_CNT + N_ROWS)        // uint counter
#define WS_OVFLIST (WS_OVF + 1)         // uint, up to N_ROWS
#define WS_SLOT (((WS_OVFLIST + N_ROWS) + 1) & ~1)  // u64 per row (8B aligned), 2*N_ROWS u32

typedef __bf16 bf16x8 __attribute__((ext_vector_type(8)));
typedef float f32x4 __attribute__((ext_vector_type(4)));

// ---------- numerics helpers ----------

__device__ __forceinline__ float mul_rn_nofma(float a, float b) {
  float r;
  asm("v_mul_f32 %0, %1, %2" : "=v"(r) : "v"(a), "v"(b));
  return r;
}

// fp32 -> bf16 bits, RNE (error <= 2^-8 rel; the margin derivation assumes this).
__device__ __forceinline__ unsigned int f2bf(float f) {
  unsigned int u = __float_as_uint(f);
  return (u + 0x7FFFu + ((u >> 16) & 1u)) >> 16;
}

// Exact np matmul replica: single ascending-d fmaf chain (bit-proven rounds 1-5).
__device__ float dot_chain(const float* __restrict__ zp, const float* __restrict__ wp) {
  float acc = 0.0f;
#pragma unroll 8
  for (int d4 = 0; d4 < 64; ++d4) {
    const float4 a = *(const float4*)(zp + d4 * 4);
    const float4 b = *(const float4*)(wp + d4 * 4);
    acc = fmaf(a.x, b.x, acc);
    acc = fmaf(a.y, b.y, acc);
    acc = fmaf(a.z, b.z, acc);
    acc = fmaf(a.w, b.w, acc);
  }
  return acc;
}

// global -> LDS 16B DMA (wave-uniform LDS base + lane*16).
__device__ __forceinline__ void glds16(const void* g, void* l) {
  __builtin_amdgcn_global_load_lds(
      (const __attribute__((address_space(1))) void*)(unsigned long long)(size_t)g,
      (__attribute__((address_space(3))) void*)(unsigned int)(size_t)l, 16, 0, 0);
}

// ---------- kernels ----------

// FUSED precvt+norms: one pass over z and W computes the exact numpy-pairwise
// norms (reduction structure UNCHANGED - bit-exact dist replication depends on
// it), the screen cut, AND emits the bf16 copies (was a separate full re-read).
__global__ void prep_kernel(const float* __restrict__ z, const float* __restrict__ W,
                            float* __restrict__ ws, unsigned short* __restrict__ outu) {
  const int tid = threadIdx.x;
  const int l = tid & 63, w = tid >> 6;
  const int j = l & 7, b = (l >> 3) & 1, rw = l >> 4;
  const int row = blockIdx.x * 16 + w * 4 + rw;  // 0 .. 73727
  const bool isz = (row < N_ROWS);
  const float* src = isz ? (z + (size_t)row * DIM + b * 128)
                         : (W + (size_t)(row - N_ROWS) * DIM + b * 128);
  unsigned short* dst = isz ? (outu + OUT_ZBF_U16 + (size_t)row * DIM + b * 128)
                            : (outu + OUT_WBF_U16 + (size_t)(row - N_ROWS) * DIM + b * 128);
  float a0 = src[j];
  dst[j] = (unsigned short)f2bf(a0);
  float r = mul_rn_nofma(a0, a0);
  float s = fabsf(a0);
  for (int i = 8; i < 128; i += 8) {
    const float v = src[i + j];
    dst[i + j] = (unsigned short)f2bf(v);
    r = r + mul_rn_nofma(v, v);
    s = s + fabsf(v);
  }
  // exact numpy pairwise tree: ((r0+r1)+(r2+r3))+((r4+r5)+(r6+r7)), then blk0+blk1
  r = r + __shfl_xor(r, 1, 64);
  r = r + __shfl_xor(r, 2, 64);
  r = r + __shfl_xor(r, 4, 64);
  r = r + __shfl_xor(r, 8, 64);
  s = s + __shfl_xor(s, 1, 64);
  s = s + __shfl_xor(s, 2, 64);
  s = s + __shfl_xor(s, 4, 64);
  s = s + __shfl_xor(s, 8, 64);
  if ((l & 15) == 0) {
    if (isz) {
      ws[WS_ZNORM + row] = r;
      const float margin = 2.0e-6f * s + 4.0e-5f;
      ws[WS_MARGIN + row] = margin;
      ws[WS_CUT0 + row] = 3.10f * sqrtf(r) * 7.0467e-5f - margin;
      ((unsigned int*)ws)[WS_CNT + row] = 0u;
    } else {
      ws[WS_WNORM + (row - N_ROWS)] = r;
    }
  }
  if (blockIdx.x == 0 && tid == 0) {
    ws[WS_LOSS] = 0.0f;
    ((unsigned int*)ws)[WS_OVF] = 0u;
  }
}

// bf16 MFMA screen GEMM, 128x128/block, 2x2 waves of 64x64, BK=32.
// NEW vs round 1:
//  - 3-buffer pipeline with COUNTED vmcnt (T3+T4): 2 stages always in flight,
//    raw s_barrier (no vmcnt(0) drain in steady state).
//  - Fixed swizzle for 64-B rows: chunk = lq ^ ((row>>1)&3). Per 16-lane
//    quarter each (row-parity, chunk) pair appears exactly 2x -> 2-way = free.
//  - T1 XCD swizzle: XCD k owns y-strips [k*64,(k+1)*64) -> each z-tile lives
//    in exactly one L2; W (4 MB) is L2-resident per XCD.
//  - T5 setprio around the MFMA cluster.
// MFMA K-slice order unchanged (ascending 32-col slices) -> acc bits identical
// to the validated kernel -> candidate set & margin proof intact.
__global__ __launch_bounds__(256) void gemm_screen_kernel(
    const unsigned short* __restrict__ zbf, const unsigned short* __restrict__ wbf,
    float* __restrict__ ws, uint2* __restrict__ candp) {
  __shared__ __align__(16) unsigned short As[3][128][32];
  __shared__ __align__(16) unsigned short Bs[3][128][32];
  __shared__ float cutbuf[128];

  const int tid = threadIdx.x;
  const int w = tid >> 6, l = tid & 63;
  const int lr = l & 15, lq = l >> 4;
  const int wr = (w >> 1) * 64, wc = (w & 1) * 64;

  // XCD-aware swizzle (bijective: 32768 = 8 * 4096): XCD gets contiguous
  // y-strips; within a strip it sweeps all 64 col-blocks.
  const int bid = blockIdx.x;
  const int swz = (bid & 7) * 4096 + (bid >> 3);
  const int rowBase = (swz >> 6) * 128, colBase = (swz & 63) * 128;

  unsigned int* cntp = (unsigned int*)ws + WS_CNT;

  if (tid < 128) cutbuf[tid] = ws[WS_CUT0 + rowBase + tid];
  // visibility covered by the first loop barrier

  f32x4 acc[4][4];
#pragma unroll
  for (int mi = 0; mi < 4; ++mi)
#pragma unroll
    for (int ni = 0; ni < 4; ++ni) acc[mi][ni] = (f32x4){0.f, 0.f, 0.f, 0.f};

  // Staging: glds16 dest is linear (wave base + lane*16): lane -> row base+l/4,
  // chunk l&3. Swizzle applied on the GLOBAL source: ga = (l&3) ^ ((row>>1)&3)
  // = (l&3) ^ ((l>>3)&3). Read side applies the same involution.
  const int ga = (l & 3) ^ ((l >> 3) & 3);
  auto STAGE = [&](int c, int b) {
#pragma unroll
    for (int j = 0; j < 2; ++j) {
      const int r_l = w * 32 + j * 16 + (l >> 2);
      glds16(zbf + (size_t)(rowBase + r_l) * DIM + c * 32 + ga * 8,
             &As[b][w * 32 + j * 16][0]);
      glds16(wbf + (size_t)(colBase + r_l) * DIM + c * 32 + ga * 8,
             &Bs[b][w * 32 + j * 16][0]);
    }
  };

  auto COMPUTE = [&](int b) {
    bf16x8 af[4], bfr[4];
    const int ch = (lq ^ ((lr >> 1) & 3)) * 8;
#pragma unroll
    for (int mi = 0; mi < 4; ++mi) af[mi] = *(const bf16x8*)&As[b][wr + mi * 16 + lr][ch];
#pragma unroll
    for (int ni = 0; ni < 4; ++ni) bfr[ni] = *(const bf16x8*)&Bs[b][wc + ni * 16 + lr][ch];
    __builtin_amdgcn_s_setprio(1);
#pragma unroll
    for (int mi = 0; mi < 4; ++mi)
#pragma unroll
      for (int ni = 0; ni < 4; ++ni)
        acc[mi][ni] =
            __builtin_amdgcn_mfma_f32_16x16x32_bf16(af[mi], bfr[ni], acc[mi][ni], 0, 0, 0);
    __builtin_amdgcn_s_setprio(0);
  };

  STAGE(0, 0);
  STAGE(1, 1);
  STAGE(2, 2);  // 12 glds16/thread in flight
#pragma unroll
  for (int c = 0; c < 8; ++c) {
    // counted wait: stage c landed; stages c+1, c+2 (8 loads) stay in flight
    if (c < 6)
      asm volatile("s_waitcnt vmcnt(8)" ::: "memory");
    else if (c == 6)
      asm volatile("s_waitcnt vmcnt(4)" ::: "memory");
    else
      asm volatile("s_waitcnt vmcnt(0)" ::: "memory");
    __builtin_amdgcn_sched_barrier(0);
    __builtin_amdgcn_s_barrier();  // all waves' stage c landed
    __builtin_amdgcn_sched_barrier(0);
    COMPUTE(c % 3);
    __builtin_amdgcn_sched_barrier(0);
    __builtin_amdgcn_s_barrier();  // all waves done reading buf c%3
    if (c < 5) STAGE(c + 3, c % 3);  // overwrite it (DMA lands behind the reads)
  }

  // Append-only epilogue. C/D layout (validated): col = lane&15, row = (lane>>4)*4 + reg
#pragma unroll
  for (int mi = 0; mi < 4; ++mi)
#pragma unroll
    for (int r = 0; r < 4; ++r) {
      const int lrow = wr + mi * 16 + lq * 4 + r;
      const float cut = cutbuf[lrow];
#pragma unroll
      for (int ni = 0; ni < 4; ++ni) {
        if (acc[mi][ni][r] >= cut) {
          const int grow = rowBase + lrow;
          const int gcol = colBase + wc + ni * 16 + lr;
          const unsigned int pos = atomicAdd(&cntp[grow], 1u);
          if (pos < CAP) {
            uint2 e;
            e.x = __float_as_uint(acc[mi][ni][r]);
            e.y = (unsigned int)gcol;
            candp[(size_t)grow * CAP + pos] = e;
          }
        }
      }
    }
}

// One WAVE per row. Lanes 0..cv-1 load candidates coalesced; shuffle-reduce
// candmax; rigor gate unchanged. Survivors run the exact np dot_chain in
// parallel lanes; argmin via packed (dist_bits<<32 | k) key (dist ~ 256 > 0 ->
// uint order = float order; ties -> lowest k = np.argmin). Fallback rows get a
// -1 sentinel index; gather_loss resolves them from the u64 slots (removes the
// separate fallback_write launch).
__global__ void recheck_kernel(const float* __restrict__ z, const float* __restrict__ W,
                               float* __restrict__ ws, const uint2* __restrict__ candp,
                               float* __restrict__ out) {
  const int lane = threadIdx.x & 63;
  const int row = blockIdx.x * 4 + (threadIdx.x >> 6);
  const unsigned int cv = ((const unsigned int*)ws)[WS_CNT + row];
  const float margin = ws[WS_MARGIN + row];
  const float cut0 = ws[WS_CUT0 + row];
  bool fb = (cv == 0u) || (cv > CAP);
  uint2 e;
  e.x = 0u; e.y = 0u;
  float av = -3.4e38f;
  if (!fb && lane < (int)cv) {
    e = candp[(size_t)row * CAP + lane];
    av = __uint_as_float(e.x);
  }
  float candmax = av;
#pragma unroll
  for (int s = 1; s < 64; s <<= 1) candmax = fmaxf(candmax, __shfl_xor(candmax, s, 64));
  if (!fb && candmax - margin < cut0) fb = true;  // cannot prove superset -> exact scan
  if (fb) {
    if (lane == 0) {
      ((unsigned long long*)((unsigned int*)ws + WS_SLOT))[row] = ~0ull;
      const unsigned int p = atomicAdd(&((unsigned int*)ws)[WS_OVF], 1u);
      ((unsigned int*)ws)[WS_OVFLIST + p] = (unsigned int)row;
      out[IDX_OFF + row] = -1.0f;  // sentinel: resolved by gather_loss
    }
    return;
  }
  const float fcut = candmax - margin;
  unsigned long long key = ~0ull;
  if (lane < (int)cv && av >= fcut) {  // below final cut: cannot be argmin
    const int k = (int)e.y;
    const float zn = ws[WS_ZNORM + row];
    const float m = dot_chain(z + (size_t)row * DIM, W + (size_t)k * DIM);
    const float dist = (zn + ws[WS_WNORM + k]) - 2.0f * m;
    key = ((unsigned long long)__float_as_uint(dist) << 32) | (unsigned int)k;
  }
#pragma unroll
  for (int s = 1; s < 64; s <<= 1) {
    const unsigned long long o = (unsigned long long)__shfl_xor((long long)key, s, 64);
    key = (o < key) ? o : key;
  }
  if (lane == 0) out[IDX_OFF + row] = (float)(unsigned int)(key & 0xffffffffull);
}

// Grid-parallel exact fallback: work item = (queued row, 256-code chunk). Each
// thread one code -> exact np dist; block-reduce min; u64 atomicMin combine.
__global__ void fallback_compute(const float* __restrict__ z, const float* __restrict__ W,
                                 float* __restrict__ ws) {
  __shared__ unsigned long long part[4];
  const unsigned int n = ((const unsigned int*)ws)[WS_OVF];
  unsigned long long* slots = (unsigned long long*)((unsigned int*)ws + WS_SLOT);
  const unsigned int total = n * 32u;
  for (unsigned int item = blockIdx.x; item < total; item += gridDim.x) {
    const int row = (int)((const unsigned int*)ws)[WS_OVFLIST + (item >> 5)];
    const int k = (int)(item & 31u) * 256 + threadIdx.x;
    const float zn = ws[WS_ZNORM + row];
    const float m = dot_chain(z + (size_t)row * DIM, W + (size_t)k * DIM);
    const float dist = (zn + ws[WS_WNORM + k]) - 2.0f * m;
    unsigned long long key =
        ((unsigned long long)__float_as_uint(dist) << 32) | (unsigned int)k;
#pragma unroll
    for (int s = 1; s < 64; s <<= 1) {
      const unsigned long long o = __shfl_xor((long long)key, s, 64);
      key = (o < key) ? o : key;
    }
    if ((threadIdx.x & 63) == 0) part[threadIdx.x >> 6] = key;
    __syncthreads();
    if (threadIdx.x == 0) {
      unsigned long long b = part[0];
      b = (part[1] < b) ? part[1] : b;
      b = (part[2] < b) ? part[2] : b;
      b = (part[3] < b) ? part[3] : b;
      atomicMin(&slots[row], b);
    }
    __syncthreads();
  }
}

// 64 rows/block: gather W[idx], quantized_st = z + (q - z), loss partial sums.
// Rows with the -1 sentinel read their exact-fallback result from the u64 slot.
__global__ void gather_loss_kernel(const float* __restrict__ z, const float* __restrict__ W,
                                   float* __restrict__ out, float* __restrict__ ws) {
  const int tid = threadIdx.x;
  const int rowBase = blockIdx.x * 64;
  float lsum = 0.0f;
  for (int p = 0; p < 16; ++p) {
    const int row = rowBase + p * 4 + (tid >> 6);
    const int c4 = tid & 63;
    int idx = (int)out[IDX_OFF + row];
    if (idx < 0) {
      const unsigned long long key =
          ((const unsigned long long*)((const unsigned int*)ws + WS_SLOT))[row];
      idx = (int)(unsigned int)(key & 0xffffffffull);
      out[IDX_OFF + row] = (float)idx;  // all 64 threads write same value: benign
    }
    const float4 zv = *(const float4*)(z + (size_t)row * DIM + c4 * 4);
    const float4 qv = *(const float4*)(W + (size_t)idx * DIM + c4 * 4);
    float4 t, o;
    t.x = qv.x - zv.x; t.y = qv.y - zv.y; t.z = qv.z - zv.z; t.w = qv.w - zv.w;
    o.x = zv.x + t.x;  o.y = zv.y + t.y;  o.z = zv.z + t.z;  o.w = zv.w + t.w;
    *(float4*)(out + (size_t)row * DIM + c4 * 4) = o;
    lsum += t.x * t.x + t.y * t.y + t.z * t.z + t.w * t.w;
  }
#pragma unroll
  for (int m = 1; m < 64; m <<= 1) lsum += __shfl_xor(lsum, m, 64);
  __shared__ float part[4];
  if ((tid & 63) == 0) part[tid >> 6] = lsum;
  __syncthreads();
  if (tid == 0) atomicAdd(&ws[WS_LOSS], (part[0] + part[1]) + (part[2] + part[3]));
}

__global__ void finalize_kernel(const float* __restrict__ ws, float* __restrict__ out) {
  if (threadIdx.x == 0 && blockIdx.x == 0) {
    const float mean = ws[WS_LOSS] / (float)(N_ROWS * DIM);
    out[LOSS_OFF] = mean + 0.25f * mean;
  }
}

extern "C" void kernel_launch(void* const* d_in, const int* in_sizes, int n_in,
                              void* d_out, int out_size, void* d_ws, size_t ws_size,
                              hipStream_t stream) {
  (void)in_sizes; (void)n_in; (void)out_size; (void)ws_size;
  const float* z = (const float*)d_in[0];
  const float* W = (const float*)d_in[1];
  float* out = (float*)d_out;
  float* ws = (float*)d_ws;
  unsigned short* outu = (unsigned short*)d_out;
  const unsigned short* wbf = outu + OUT_WBF_U16;
  const unsigned short* zbf = outu + OUT_ZBF_U16;
  uint2* candp = (uint2*)((float*)d_out + OUT_CAND_F);

  hipLaunchKernelGGL(prep_kernel, dim3((N_ROWS + K_CODES) / 16), dim3(256), 0, stream,
                     z, W, ws, outu);
  hipLaunchKernelGGL(gemm_screen_kernel, dim3((K_CODES / 128) * (N_ROWS / 128)),
                     dim3(256), 0, stream, zbf, wbf, ws, candp);
  hipLaunchKernelGGL(recheck_kernel, dim3(N_ROWS / 4), dim3(256), 0, stream,
                     z, W, ws, candp, out);
  hipLaunchKernelGGL(fallback_compute, dim3(2048), dim3(256), 0, stream, z, W, ws);
  hipLaunchKernelGGL(gather_loss_kernel, dim3(N_ROWS / 64), dim3(256), 0, stream,
                     z, W, out, ws);
  hipLaunchKernelGGL(finalize_kernel, dim3(1), dim3(64), 0, stream, ws, out);
}

// Round 3
// 1274.324 us; speedup vs baseline: 1.1529x; 1.1529x over previous
//
#include <hip/hip_runtime.h>

#define N_ROWS 65536
#define K_CODES 8192
#define DIM 256
#define CAP 56

// d_out layout (floats): [quantized_st 65536*256][loss 1][indices 65536]
#define LOSS_OFF (N_ROWS * DIM)
#define IDX_OFF (LOSS_OFF + 1)
// scratch inside d_out's quantized region (consumed before gather overwrites):
#define OUT_WBF_U16 0              // W_bf: 8192*256 u16  (4 MB)
#define OUT_ZBF_U16 2097152        // z_bf: 65536*256 u16 (32 MB)
#define OUT_CAND_F 9437184         // cand: 65536*56 uint2 (29.36 MB); ends exactly at 16777216

// d_ws layout (4-byte units), ~1.85 MB total
#define WS_LOSS 0
#define WS_ZNORM 64
#define WS_WNORM (WS_ZNORM + N_ROWS)
#define WS_MARGIN (WS_WNORM + K_CODES)
#define WS_CUT0 (WS_MARGIN + N_ROWS)
#define WS_CNT (WS_CUT0 + N_ROWS)       // uint
#define WS_OVF (WS_CNT + N_ROWS)        // uint counter
#define WS_OVFLIST (WS_OVF + 1)         // uint, up to N_ROWS
#define WS_SLOT (((WS_OVFLIST + N_ROWS) + 1) & ~1)  // u64 per row (8B aligned), 2*N_ROWS u32

typedef __bf16 bf16x8 __attribute__((ext_vector_type(8)));
typedef float f32x4 __attribute__((ext_vector_type(4)));

// ---------- numerics helpers ----------

__device__ __forceinline__ float mul_rn_nofma(float a, float b) {
  float r;
  asm("v_mul_f32 %0, %1, %2" : "=v"(r) : "v"(a), "v"(b));
  return r;
}

// fp32 -> bf16 bits, RNE (error <= 2^-8 rel; the margin derivation assumes this).
__device__ __forceinline__ unsigned int f2bf(float f) {
  unsigned int u = __float_as_uint(f);
  return (u + 0x7FFFu + ((u >> 16) & 1u)) >> 16;
}

// Exact np matmul replica: single ascending-d fmaf chain (bit-proven rounds 1-5).
__device__ float dot_chain(const float* __restrict__ zp, const float* __restrict__ wp) {
  float acc = 0.0f;
#pragma unroll 8
  for (int d4 = 0; d4 < 64; ++d4) {
    const float4 a = *(const float4*)(zp + d4 * 4);
    const float4 b = *(const float4*)(wp + d4 * 4);
    acc = fmaf(a.x, b.x, acc);
    acc = fmaf(a.y, b.y, acc);
    acc = fmaf(a.z, b.z, acc);
    acc = fmaf(a.w, b.w, acc);
  }
  return acc;
}

// global -> LDS 16B DMA (wave-uniform LDS base + lane*16).
__device__ __forceinline__ void glds16(const void* g, void* l) {
  __builtin_amdgcn_global_load_lds(
      (const __attribute__((address_space(1))) void*)(unsigned long long)(size_t)g,
      (__attribute__((address_space(3))) void*)(unsigned int)(size_t)l, 16, 0, 0);
}

// ---------- kernels ----------

// FUSED precvt+norms: one pass over z and W computes the exact numpy-pairwise
// norms (reduction structure UNCHANGED - bit-exact dist replication depends on
// it), the screen cut, AND emits the bf16 copies.
__global__ void prep_kernel(const float* __restrict__ z, const float* __restrict__ W,
                            float* __restrict__ ws, unsigned short* __restrict__ outu) {
  const int tid = threadIdx.x;
  const int l = tid & 63, w = tid >> 6;
  const int j = l & 7, b = (l >> 3) & 1, rw = l >> 4;
  const int row = blockIdx.x * 16 + w * 4 + rw;  // 0 .. 73727
  const bool isz = (row < N_ROWS);
  const float* src = isz ? (z + (size_t)row * DIM + b * 128)
                         : (W + (size_t)(row - N_ROWS) * DIM + b * 128);
  unsigned short* dst = isz ? (outu + OUT_ZBF_U16 + (size_t)row * DIM + b * 128)
                            : (outu + OUT_WBF_U16 + (size_t)(row - N_ROWS) * DIM + b * 128);
  float a0 = src[j];
  dst[j] = (unsigned short)f2bf(a0);
  float r = mul_rn_nofma(a0, a0);
  float s = fabsf(a0);
  for (int i = 8; i < 128; i += 8) {
    const float v = src[i + j];
    dst[i + j] = (unsigned short)f2bf(v);
    r = r + mul_rn_nofma(v, v);
    s = s + fabsf(v);
  }
  // exact numpy pairwise tree: ((r0+r1)+(r2+r3))+((r4+r5)+(r6+r7)), then blk0+blk1
  r = r + __shfl_xor(r, 1, 64);
  r = r + __shfl_xor(r, 2, 64);
  r = r + __shfl_xor(r, 4, 64);
  r = r + __shfl_xor(r, 8, 64);
  s = s + __shfl_xor(s, 1, 64);
  s = s + __shfl_xor(s, 2, 64);
  s = s + __shfl_xor(s, 4, 64);
  s = s + __shfl_xor(s, 8, 64);
  if ((l & 15) == 0) {
    if (isz) {
      ws[WS_ZNORM + row] = r;
      const float margin = 2.0e-6f * s + 4.0e-5f;
      ws[WS_MARGIN + row] = margin;
      ws[WS_CUT0 + row] = 3.10f * sqrtf(r) * 7.0467e-5f - margin;
      ((unsigned int*)ws)[WS_CNT + row] = 0u;
    } else {
      ws[WS_WNORM + (row - N_ROWS)] = r;
    }
  }
  if (blockIdx.x == 0 && tid == 0) {
    ws[WS_LOSS] = 0.0f;
    ((unsigned int*)ws)[WS_OVF] = 0u;
  }
}

// bf16 MFMA screen GEMM - W-RESIDENT, BARRIER-FREE structure.
// Block = 4 waves (2x2 of 64x64), colBase fixed; W-tile (128 cols x 256 K =
// 64 KB) staged ONCE into LDS (swizzled via per-lane pre-swizzled global
// source; glds dest is linear). Then 32 z row-strips are processed with ZERO
// barriers: A-fragments load directly from global (z strip is L2-hot: all 64
// col-blocks of a row-group run concurrently under x-major dispatch),
// B-fragments via ds_read_b128 with the round-0-proven conflict-free
// chunk^(lr&7) pattern. Loads of k-step ks+1 hide under ks's 16 MFMA
// (~310 SIMD-cy) with no barrier to stop scheduling; 2 blocks/CU free-run.
// MFMA K-slice order unchanged (ascending 32-col slices, lq = k-subgroup) ->
// acc bits identical to the validated kernel -> candidate set & proof intact.
__global__ __launch_bounds__(256) void gemm_screen_kernel(
    const unsigned short* __restrict__ zbf, const unsigned short* __restrict__ wbf,
    float* __restrict__ ws, uint2* __restrict__ candp) {
  __shared__ __align__(16) unsigned short Bs[128][256];  // 64 KB, W-cols x K

  const int tid = threadIdx.x;
  const int w = tid >> 6, l = tid & 63;
  const int lr = l & 15, lq = l >> 4;
  const int wr = (w >> 1) * 64, wc = (w & 1) * 64;
  const int colBase = blockIdx.x * 128;
  const int g = blockIdx.y;  // row group 0..15 (32 strips each)

  unsigned int* cntp = (unsigned int*)ws + WS_CNT;

  // One-time W staging. Wave w fills rows [w*32, w*32+32): per iter 2 rows
  // (1 KB = one glds16 wave-op). Lane l -> row r0+(l>>5), 16B chunk l&31.
  // Stored chunk c holds source chunk c^(r&7) (involution; read applies same).
  {
    const int rhalf = l >> 5, cc = l & 31;
#pragma unroll
    for (int t = 0; t < 16; ++t) {
      const int r0 = w * 32 + t * 2;
      const int r = r0 + rhalf;
      glds16(wbf + (size_t)(colBase + r) * DIM + ((cc ^ (r & 7)) * 8), &Bs[r0][0]);
    }
  }
  __syncthreads();  // drains vmcnt: W resident. The ONLY barrier in the kernel.

  const unsigned short* zb0 = zbf + (size_t)(wr + lr) * DIM + lq * 8;

  for (int s = 0; s < 32; ++s) {
    const int rowBase = g * 4096 + s * 128;
    const unsigned short* za = zb0 + (size_t)rowBase * DIM;

    f32x4 acc[4][4];
#pragma unroll
    for (int mi = 0; mi < 4; ++mi)
#pragma unroll
      for (int ni = 0; ni < 4; ++ni) acc[mi][ni] = (f32x4){0.f, 0.f, 0.f, 0.f};

#pragma unroll
    for (int ks = 0; ks < 8; ++ks) {
      bf16x8 af[4], bfr[4];
#pragma unroll
      for (int mi = 0; mi < 4; ++mi)
        af[mi] = *(const bf16x8*)(za + (size_t)mi * 16 * DIM + ks * 32);
#pragma unroll
      for (int ni = 0; ni < 4; ++ni) {
        const int br = wc + ni * 16 + lr;
        bfr[ni] = *(const bf16x8*)&Bs[br][((ks * 4 + lq) ^ (lr & 7)) * 8];
      }
#pragma unroll
      for (int mi = 0; mi < 4; ++mi)
#pragma unroll
        for (int ni = 0; ni < 4; ++ni)
          acc[mi][ni] =
              __builtin_amdgcn_mfma_f32_16x16x32_bf16(af[mi], bfr[ni], acc[mi][ni], 0, 0, 0);
    }

    // Append-only epilogue. C/D layout (validated): col = lane&15,
    // row = (lane>>4)*4 + reg. Cuts: 4 consecutive rows per mi -> one float4
    // (L2-hot), no LDS, no barrier.
#pragma unroll
    for (int mi = 0; mi < 4; ++mi) {
      const float4 cutv =
          *(const float4*)(ws + WS_CUT0 + rowBase + wr + mi * 16 + lq * 4);
      const float cuta[4] = {cutv.x, cutv.y, cutv.z, cutv.w};
#pragma unroll
      for (int r = 0; r < 4; ++r) {
        const int lrow = wr + mi * 16 + lq * 4 + r;
        const float cut = cuta[r];
#pragma unroll
        for (int ni = 0; ni < 4; ++ni) {
          if (acc[mi][ni][r] >= cut) {
            const int grow = rowBase + lrow;
            const int gcol = colBase + wc + ni * 16 + lr;
            const unsigned int pos = atomicAdd(&cntp[grow], 1u);
            if (pos < CAP) {
              uint2 e;
              e.x = __float_as_uint(acc[mi][ni][r]);
              e.y = (unsigned int)gcol;
              candp[(size_t)grow * CAP + pos] = e;
            }
          }
        }
      }
    }
  }
}

// One WAVE per row. Lanes 0..cv-1 load candidates coalesced; shuffle-reduce
// candmax; rigor gate unchanged. Survivors run the exact np dot_chain in
// parallel lanes; argmin via packed (dist_bits<<32 | k) key (dist ~ 256 > 0 ->
// uint order = float order; ties -> lowest k = np.argmin). Fallback rows get a
// -1 sentinel index; gather_loss resolves them from the u64 slots.
__global__ void recheck_kernel(const float* __restrict__ z, const float* __restrict__ W,
                               float* __restrict__ ws, const uint2* __restrict__ candp,
                               float* __restrict__ out) {
  const int lane = threadIdx.x & 63;
  const int row = blockIdx.x * 4 + (threadIdx.x >> 6);
  const unsigned int cv = ((const unsigned int*)ws)[WS_CNT + row];
  const float margin = ws[WS_MARGIN + row];
  const float cut0 = ws[WS_CUT0 + row];
  bool fb = (cv == 0u) || (cv > CAP);
  uint2 e;
  e.x = 0u; e.y = 0u;
  float av = -3.4e38f;
  if (!fb && lane < (int)cv) {
    e = candp[(size_t)row * CAP + lane];
    av = __uint_as_float(e.x);
  }
  float candmax = av;
#pragma unroll
  for (int s = 1; s < 64; s <<= 1) candmax = fmaxf(candmax, __shfl_xor(candmax, s, 64));
  if (!fb && candmax - margin < cut0) fb = true;  // cannot prove superset -> exact scan
  if (fb) {
    if (lane == 0) {
      ((unsigned long long*)((unsigned int*)ws + WS_SLOT))[row] = ~0ull;
      const unsigned int p = atomicAdd(&((unsigned int*)ws)[WS_OVF], 1u);
      ((unsigned int*)ws)[WS_OVFLIST + p] = (unsigned int)row;
      out[IDX_OFF + row] = -1.0f;  // sentinel: resolved by gather_loss
    }
    return;
  }
  const float fcut = candmax - margin;
  unsigned long long key = ~0ull;
  if (lane < (int)cv && av >= fcut) {  // below final cut: cannot be argmin
    const int k = (int)e.y;
    const float zn = ws[WS_ZNORM + row];
    const float m = dot_chain(z + (size_t)row * DIM, W + (size_t)k * DIM);
    const float dist = (zn + ws[WS_WNORM + k]) - 2.0f * m;
    key = ((unsigned long long)__float_as_uint(dist) << 32) | (unsigned int)k;
  }
#pragma unroll
  for (int s = 1; s < 64; s <<= 1) {
    const unsigned long long o = (unsigned long long)__shfl_xor((long long)key, s, 64);
    key = (o < key) ? o : key;
  }
  if (lane == 0) out[IDX_OFF + row] = (float)(unsigned int)(key & 0xffffffffull);
}

// Grid-parallel exact fallback: work item = (queued row, 256-code chunk). Each
// thread one code -> exact np dist; block-reduce min; u64 atomicMin combine.
__global__ void fallback_compute(const float* __restrict__ z, const float* __restrict__ W,
                                 float* __restrict__ ws) {
  __shared__ unsigned long long part[4];
  const unsigned int n = ((const unsigned int*)ws)[WS_OVF];
  unsigned long long* slots = (unsigned long long*)((unsigned int*)ws + WS_SLOT);
  const unsigned int total = n * 32u;
  for (unsigned int item = blockIdx.x; item < total; item += gridDim.x) {
    const int row = (int)((const unsigned int*)ws)[WS_OVFLIST + (item >> 5)];
    const int k = (int)(item & 31u) * 256 + threadIdx.x;
    const float zn = ws[WS_ZNORM + row];
    const float m = dot_chain(z + (size_t)row * DIM, W + (size_t)k * DIM);
    const float dist = (zn + ws[WS_WNORM + k]) - 2.0f * m;
    unsigned long long key =
        ((unsigned long long)__float_as_uint(dist) << 32) | (unsigned int)k;
#pragma unroll
    for (int s = 1; s < 64; s <<= 1) {
      const unsigned long long o = __shfl_xor((long long)key, s, 64);
      key = (o < key) ? o : key;
    }
    if ((threadIdx.x & 63) == 0) part[threadIdx.x >> 6] = key;
    __syncthreads();
    if (threadIdx.x == 0) {
      unsigned long long b = part[0];
      b = (part[1] < b) ? part[1] : b;
      b = (part[2] < b) ? part[2] : b;
      b = (part[3] < b) ? part[3] : b;
      atomicMin(&slots[row], b);
    }
    __syncthreads();
  }
}

// 64 rows/block: gather W[idx], quantized_st = z + (q - z), loss partial sums.
// Rows with the -1 sentinel read their exact-fallback result from the u64 slot.
__global__ void gather_loss_kernel(const float* __restrict__ z, const float* __restrict__ W,
                                   float* __restrict__ out, float* __restrict__ ws) {
  const int tid = threadIdx.x;
  const int rowBase = blockIdx.x * 64;
  float lsum = 0.0f;
  for (int p = 0; p < 16; ++p) {
    const int row = rowBase + p * 4 + (tid >> 6);
    const int c4 = tid & 63;
    int idx = (int)out[IDX_OFF + row];
    if (idx < 0) {
      const unsigned long long key =
          ((const unsigned long long*)((const unsigned int*)ws + WS_SLOT))[row];
      idx = (int)(unsigned int)(key & 0xffffffffull);
      out[IDX_OFF + row] = (float)idx;  // all 64 threads write same value: benign
    }
    const float4 zv = *(const float4*)(z + (size_t)row * DIM + c4 * 4);
    const float4 qv = *(const float4*)(W + (size_t)idx * DIM + c4 * 4);
    float4 t, o;
    t.x = qv.x - zv.x; t.y = qv.y - zv.y; t.z = qv.z - zv.z; t.w = qv.w - zv.w;
    o.x = zv.x + t.x;  o.y = zv.y + t.y;  o.z = zv.z + t.z;  o.w = zv.w + t.w;
    *(float4*)(out + (size_t)row * DIM + c4 * 4) = o;
    lsum += t.x * t.x + t.y * t.y + t.z * t.z + t.w * t.w;
  }
#pragma unroll
  for (int m = 1; m < 64; m <<= 1) lsum += __shfl_xor(lsum, m, 64);
  __shared__ float part[4];
  if ((tid & 63) == 0) part[tid >> 6] = lsum;
  __syncthreads();
  if (tid == 0) atomicAdd(&ws[WS_LOSS], (part[0] + part[1]) + (part[2] + part[3]));
}

__global__ void finalize_kernel(const float* __restrict__ ws, float* __restrict__ out) {
  if (threadIdx.x == 0 && blockIdx.x == 0) {
    const float mean = ws[WS_LOSS] / (float)(N_ROWS * DIM);
    out[LOSS_OFF] = mean + 0.25f * mean;
  }
}

extern "C" void kernel_launch(void* const* d_in, const int* in_sizes, int n_in,
                              void* d_out, int out_size, void* d_ws, size_t ws_size,
                              hipStream_t stream) {
  (void)in_sizes; (void)n_in; (void)out_size; (void)ws_size;
  const float* z = (const float*)d_in[0];
  const float* W = (const float*)d_in[1];
  float* out = (float*)d_out;
  float* ws = (float*)d_ws;
  unsigned short* outu = (unsigned short*)d_out;
  const unsigned short* wbf = outu + OUT_WBF_U16;
  const unsigned short* zbf = outu + OUT_ZBF_U16;
  uint2* candp = (uint2*)((float*)d_out + OUT_CAND_F);

  hipLaunchKernelGGL(prep_kernel, dim3((N_ROWS + K_CODES) / 16), dim3(256), 0, stream,
                     z, W, ws, outu);
  // x-major dispatch: all 64 col-blocks of a row-group run concurrently ->
  // z strips L2-hot; W-tile loaded once per block.
  hipLaunchKernelGGL(gemm_screen_kernel, dim3(K_CODES / 128, 16), dim3(256),
                     0, stream, zbf, wbf, ws, candp);
  hipLaunchKernelGGL(recheck_kernel, dim3(N_ROWS / 4), dim3(256), 0, stream,
                     z, W, ws, candp, out);
  hipLaunchKernelGGL(fallback_compute, dim3(2048), dim3(256), 0, stream, z, W, ws);
  hipLaunchKernelGGL(gather_loss_kernel, dim3(N_ROWS / 64), dim3(256), 0, stream,
                     z, W, out, ws);
  hipLaunchKernelGGL(finalize_kernel, dim3(1), dim3(64), 0, stream, ws, out);
}

// Round 4
// 987.198 us; speedup vs baseline: 1.4882x; 1.2908x over previous
//
#include <hip/hip_runtime.h>

#define N_ROWS 65536
#define K_CODES 8192
#define DIM 256
#define CAP 56

// d_out layout (floats): [quantized_st 65536*256][loss 1][indices 65536]
#define LOSS_OFF (N_ROWS * DIM)
#define IDX_OFF (LOSS_OFF + 1)
// scratch inside d_out's quantized region (consumed before gather overwrites):
#define OUT_WBF_U16 0              // W_bf: 8192*256 u16  (4 MB)
#define OUT_ZBF_U16 2097152        // z_bf: 65536*256 u16 (32 MB)
#define OUT_CAND_F 9437184         // cand: 65536*56 uint2 (29.36 MB); ends exactly at 16777216

// d_ws layout (4-byte units), ~1.85 MB total
#define WS_LOSS 0
#define WS_ZNORM 64
#define WS_WNORM (WS_ZNORM + N_ROWS)
#define WS_MARGIN (WS_WNORM + K_CODES)
#define WS_CUT0 (WS_MARGIN + N_ROWS)
#define WS_CNT (WS_CUT0 + N_ROWS)       // uint
#define WS_OVF (WS_CNT + N_ROWS)        // uint counter
#define WS_OVFLIST (WS_OVF + 1)         // uint, up to N_ROWS
#define WS_SLOT (((WS_OVFLIST + N_ROWS) + 1) & ~1)  // u64 per row (8B aligned), 2*N_ROWS u32

typedef __bf16 bf16x8 __attribute__((ext_vector_type(8)));
typedef float f32x4 __attribute__((ext_vector_type(4)));

// ---------- numerics helpers ----------

__device__ __forceinline__ float mul_rn_nofma(float a, float b) {
  float r;
  asm("v_mul_f32 %0, %1, %2" : "=v"(r) : "v"(a), "v"(b));
  return r;
}

// fp32 -> bf16 bits, RNE (error <= 2^-8 rel; the margin derivation assumes this).
__device__ __forceinline__ unsigned int f2bf(float f) {
  unsigned int u = __float_as_uint(f);
  return (u + 0x7FFFu + ((u >> 16) & 1u)) >> 16;
}

// Exact np matmul replica: single ascending-d fmaf chain (bit-proven rounds 1-5).
__device__ float dot_chain(const float* __restrict__ zp, const float* __restrict__ wp) {
  float acc = 0.0f;
#pragma unroll 8
  for (int d4 = 0; d4 < 64; ++d4) {
    const float4 a = *(const float4*)(zp + d4 * 4);
    const float4 b = *(const float4*)(wp + d4 * 4);
    acc = fmaf(a.x, b.x, acc);
    acc = fmaf(a.y, b.y, acc);
    acc = fmaf(a.z, b.z, acc);
    acc = fmaf(a.w, b.w, acc);
  }
  return acc;
}

// global -> LDS 16B DMA (wave-uniform LDS base + lane*16).
__device__ __forceinline__ void glds16(const void* g, void* l) {
  __builtin_amdgcn_global_load_lds(
      (const __attribute__((address_space(1))) void*)(unsigned long long)(size_t)g,
      (__attribute__((address_space(3))) void*)(unsigned int)(size_t)l, 16, 0, 0);
}

// ---------- kernels ----------

// FUSED precvt+norms: one pass over z and W computes the exact numpy-pairwise
// norms (reduction structure UNCHANGED - bit-exact dist replication depends on
// it), the screen cut, AND emits the bf16 copies.
__global__ void prep_kernel(const float* __restrict__ z, const float* __restrict__ W,
                            float* __restrict__ ws, unsigned short* __restrict__ outu) {
  const int tid = threadIdx.x;
  const int l = tid & 63, w = tid >> 6;
  const int j = l & 7, b = (l >> 3) & 1, rw = l >> 4;
  const int row = blockIdx.x * 16 + w * 4 + rw;  // 0 .. 73727
  const bool isz = (row < N_ROWS);
  const float* src = isz ? (z + (size_t)row * DIM + b * 128)
                         : (W + (size_t)(row - N_ROWS) * DIM + b * 128);
  unsigned short* dst = isz ? (outu + OUT_ZBF_U16 + (size_t)row * DIM + b * 128)
                            : (outu + OUT_WBF_U16 + (size_t)(row - N_ROWS) * DIM + b * 128);
  float a0 = src[j];
  dst[j] = (unsigned short)f2bf(a0);
  float r = mul_rn_nofma(a0, a0);
  float s = fabsf(a0);
  for (int i = 8; i < 128; i += 8) {
    const float v = src[i + j];
    dst[i + j] = (unsigned short)f2bf(v);
    r = r + mul_rn_nofma(v, v);
    s = s + fabsf(v);
  }
  // exact numpy pairwise tree: ((r0+r1)+(r2+r3))+((r4+r5)+(r6+r7)), then blk0+blk1
  r = r + __shfl_xor(r, 1, 64);
  r = r + __shfl_xor(r, 2, 64);
  r = r + __shfl_xor(r, 4, 64);
  r = r + __shfl_xor(r, 8, 64);
  s = s + __shfl_xor(s, 1, 64);
  s = s + __shfl_xor(s, 2, 64);
  s = s + __shfl_xor(s, 4, 64);
  s = s + __shfl_xor(s, 8, 64);
  if ((l & 15) == 0) {
    if (isz) {
      ws[WS_ZNORM + row] = r;
      const float margin = 2.0e-6f * s + 4.0e-5f;
      ws[WS_MARGIN + row] = margin;
      ws[WS_CUT0 + row] = 3.10f * sqrtf(r) * 7.0467e-5f - margin;
      ((unsigned int*)ws)[WS_CNT + row] = 0u;
    } else {
      ws[WS_WNORM + (row - N_ROWS)] = r;
    }
  }
  if (blockIdx.x == 0 && tid == 0) {
    ws[WS_LOSS] = 0.0f;
    ((unsigned int*)ws)[WS_OVF] = 0u;
  }
}

// bf16 MFMA screen GEMM, 128x128/block, 2x2 waves of 64x64, BK=32.
// Round-4 synthesis of individually-validated pieces:
//  - natural 2D dispatch (r0/r1: FETCH 134 MB, L2-friendly)
//  - 2-buffer BK=32 pipeline, 33 KB LDS (r0 occupancy: 3-4 blocks/CU)
//  - COUNTED vmcnt(4) + raw s_barrier (r2: mechanically correct) so the
//    in-flight prefetch SURVIVES the barrier (r1's __syncthreads drained it)
//  - r2-verified conflict-free involution for 64-B rows:
//    stored chunk ch holds source chunk ch^((row>>1)&3); read applies same.
// MFMA K-slice order unchanged (ascending 32-wide chunks, lane lq = k-sub) ->
// acc bits identical to validated kernels -> candidate set & proof intact.
__global__ __launch_bounds__(256) void gemm_screen_kernel(
    const unsigned short* __restrict__ zbf, const unsigned short* __restrict__ wbf,
    float* __restrict__ ws, uint2* __restrict__ candp) {
  __shared__ __align__(16) unsigned short As[2][128][32];
  __shared__ __align__(16) unsigned short Bs[2][128][32];
  __shared__ float cutbuf[128];

  const int tid = threadIdx.x;
  const int w = tid >> 6, l = tid & 63;
  const int lr = l & 15, lq = l >> 4;
  const int wr = (w >> 1) * 64, wc = (w & 1) * 64;
  const int rowBase = blockIdx.y * 128, colBase = blockIdx.x * 128;

  unsigned int* cntp = (unsigned int*)ws + WS_CNT;

  if (tid < 128) cutbuf[tid] = ws[WS_CUT0 + rowBase + tid];
  // visibility covered by the first in-loop s_barrier

  f32x4 acc[4][4];
#pragma unroll
  for (int mi = 0; mi < 4; ++mi)
#pragma unroll
    for (int ni = 0; ni < 4; ++ni) acc[mi][ni] = (f32x4){0.f, 0.f, 0.f, 0.f};

  // glds16 dest is linear: lane l -> row base + (l>>2), chunk l&3 (64-B rows).
  // Source pre-swizzled: ga = (l&3) ^ ((row>>1)&3) = (l&3) ^ ((l>>3)&3).
  const int ga = (l & 3) ^ ((l >> 3) & 3);
  auto STAGE = [&](int c, int b) {
#pragma unroll
    for (int j = 0; j < 2; ++j) {
      const int r_l = w * 32 + j * 16 + (l >> 2);
      glds16(zbf + (size_t)(rowBase + r_l) * DIM + c * 32 + ga * 8,
             &As[b][w * 32 + j * 16][0]);
      glds16(wbf + (size_t)(colBase + r_l) * DIM + c * 32 + ga * 8,
             &Bs[b][w * 32 + j * 16][0]);
    }
  };

  auto COMPUTE = [&](int b) {
    bf16x8 af[4], bfr[4];
    // row = 16-aligned + lr  ->  (row>>1)&3 = (lr>>1)&3
    const int ch = (lq ^ ((lr >> 1) & 3)) * 8;
#pragma unroll
    for (int mi = 0; mi < 4; ++mi) af[mi] = *(const bf16x8*)&As[b][wr + mi * 16 + lr][ch];
#pragma unroll
    for (int ni = 0; ni < 4; ++ni) bfr[ni] = *(const bf16x8*)&Bs[b][wc + ni * 16 + lr][ch];
#pragma unroll
    for (int mi = 0; mi < 4; ++mi)
#pragma unroll
      for (int ni = 0; ni < 4; ++ni)
        acc[mi][ni] =
            __builtin_amdgcn_mfma_f32_16x16x32_bf16(af[mi], bfr[ni], acc[mi][ni], 0, 0, 0);
  };

  STAGE(0, 0);
  STAGE(1, 1);  // 8 glds16/lane in flight (4 per stage)
#pragma unroll
  for (int c = 0; c < 8; ++c) {
    // stage c landed; stage c+1 (4 loads) stays in flight across the barrier
    if (c < 7)
      asm volatile("s_waitcnt vmcnt(4)" ::: "memory");
    else
      asm volatile("s_waitcnt vmcnt(0)" ::: "memory");
    __builtin_amdgcn_sched_barrier(0);
    __builtin_amdgcn_s_barrier();  // all waves' stage c landed
    __builtin_amdgcn_sched_barrier(0);
    COMPUTE(c & 1);  // ds_reads consumed by MFMAs (compiler lgkmcnt) pre-barrier
    __builtin_amdgcn_sched_barrier(0);
    __builtin_amdgcn_s_barrier();  // all waves done reading buf c&1
    if (c < 6) STAGE(c + 2, c & 1);  // refill it; DMA lands behind the reads
  }

  // Append-only epilogue. C/D layout (validated): col = lane&15, row = (lane>>4)*4 + reg
#pragma unroll
  for (int mi = 0; mi < 4; ++mi)
#pragma unroll
    for (int r = 0; r < 4; ++r) {
      const int lrow = wr + mi * 16 + lq * 4 + r;
      const float cut = cutbuf[lrow];
#pragma unroll
      for (int ni = 0; ni < 4; ++ni) {
        if (acc[mi][ni][r] >= cut) {
          const int grow = rowBase + lrow;
          const int gcol = colBase + wc + ni * 16 + lr;
          const unsigned int pos = atomicAdd(&cntp[grow], 1u);
          if (pos < CAP) {
            uint2 e;
            e.x = __float_as_uint(acc[mi][ni][r]);
            e.y = (unsigned int)gcol;
            candp[(size_t)grow * CAP + pos] = e;
          }
        }
      }
    }
}

// One WAVE per row. Lanes 0..cv-1 load candidates coalesced; shuffle-reduce
// candmax; rigor gate unchanged. Survivors run the exact np dot_chain in
// parallel lanes; argmin via packed (dist_bits<<32 | k) key (dist ~ 256 > 0 ->
// uint order = float order; ties -> lowest k = np.argmin). Fallback rows get a
// -1 sentinel index; gather_loss resolves them from the u64 slots.
__global__ void recheck_kernel(const float* __restrict__ z, const float* __restrict__ W,
                               float* __restrict__ ws, const uint2* __restrict__ candp,
                               float* __restrict__ out) {
  const int lane = threadIdx.x & 63;
  const int row = blockIdx.x * 4 + (threadIdx.x >> 6);
  const unsigned int cv = ((const unsigned int*)ws)[WS_CNT + row];
  const float margin = ws[WS_MARGIN + row];
  const float cut0 = ws[WS_CUT0 + row];
  bool fb = (cv == 0u) || (cv > CAP);
  uint2 e;
  e.x = 0u; e.y = 0u;
  float av = -3.4e38f;
  if (!fb && lane < (int)cv) {
    e = candp[(size_t)row * CAP + lane];
    av = __uint_as_float(e.x);
  }
  float candmax = av;
#pragma unroll
  for (int s = 1; s < 64; s <<= 1) candmax = fmaxf(candmax, __shfl_xor(candmax, s, 64));
  if (!fb && candmax - margin < cut0) fb = true;  // cannot prove superset -> exact scan
  if (fb) {
    if (lane == 0) {
      ((unsigned long long*)((unsigned int*)ws + WS_SLOT))[row] = ~0ull;
      const unsigned int p = atomicAdd(&((unsigned int*)ws)[WS_OVF], 1u);
      ((unsigned int*)ws)[WS_OVFLIST + p] = (unsigned int)row;
      out[IDX_OFF + row] = -1.0f;  // sentinel: resolved by gather_loss
    }
    return;
  }
  const float fcut = candmax - margin;
  unsigned long long key = ~0ull;
  if (lane < (int)cv && av >= fcut) {  // below final cut: cannot be argmin
    const int k = (int)e.y;
    const float zn = ws[WS_ZNORM + row];
    const float m = dot_chain(z + (size_t)row * DIM, W + (size_t)k * DIM);
    const float dist = (zn + ws[WS_WNORM + k]) - 2.0f * m;
    key = ((unsigned long long)__float_as_uint(dist) << 32) | (unsigned int)k;
  }
#pragma unroll
  for (int s = 1; s < 64; s <<= 1) {
    const unsigned long long o = (unsigned long long)__shfl_xor((long long)key, s, 64);
    key = (o < key) ? o : key;
  }
  if (lane == 0) out[IDX_OFF + row] = (float)(unsigned int)(key & 0xffffffffull);
}

// Grid-parallel exact fallback: work item = (queued row, 256-code chunk). Each
// thread one code -> exact np dist; block-reduce min; u64 atomicMin combine.
__global__ void fallback_compute(const float* __restrict__ z, const float* __restrict__ W,
                                 float* __restrict__ ws) {
  __shared__ unsigned long long part[4];
  const unsigned int n = ((const unsigned int*)ws)[WS_OVF];
  unsigned long long* slots = (unsigned long long*)((unsigned int*)ws + WS_SLOT);
  const unsigned int total = n * 32u;
  for (unsigned int item = blockIdx.x; item < total; item += gridDim.x) {
    const int row = (int)((const unsigned int*)ws)[WS_OVFLIST + (item >> 5)];
    const int k = (int)(item & 31u) * 256 + threadIdx.x;
    const float zn = ws[WS_ZNORM + row];
    const float m = dot_chain(z + (size_t)row * DIM, W + (size_t)k * DIM);
    const float dist = (zn + ws[WS_WNORM + k]) - 2.0f * m;
    unsigned long long key =
        ((unsigned long long)__float_as_uint(dist) << 32) | (unsigned int)k;
#pragma unroll
    for (int s = 1; s < 64; s <<= 1) {
      const unsigned long long o = __shfl_xor((long long)key, s, 64);
      key = (o < key) ? o : key;
    }
    if ((threadIdx.x & 63) == 0) part[threadIdx.x >> 6] = key;
    __syncthreads();
    if (threadIdx.x == 0) {
      unsigned long long b = part[0];
      b = (part[1] < b) ? part[1] : b;
      b = (part[2] < b) ? part[2] : b;
      b = (part[3] < b) ? part[3] : b;
      atomicMin(&slots[row], b);
    }
    __syncthreads();
  }
}

// 64 rows/block: gather W[idx], quantized_st = z + (q - z), loss partial sums.
// Rows with the -1 sentinel read their exact-fallback result from the u64 slot.
__global__ void gather_loss_kernel(const float* __restrict__ z, const float* __restrict__ W,
                                   float* __restrict__ out, float* __restrict__ ws) {
  const int tid = threadIdx.x;
  const int rowBase = blockIdx.x * 64;
  float lsum = 0.0f;
  for (int p = 0; p < 16; ++p) {
    const int row = rowBase + p * 4 + (tid >> 6);
    const int c4 = tid & 63;
    int idx = (int)out[IDX_OFF + row];
    if (idx < 0) {
      const unsigned long long key =
          ((const unsigned long long*)((const unsigned int*)ws + WS_SLOT))[row];
      idx = (int)(unsigned int)(key & 0xffffffffull);
      out[IDX_OFF + row] = (float)idx;  // all 64 threads write same value: benign
    }
    const float4 zv = *(const float4*)(z + (size_t)row * DIM + c4 * 4);
    const float4 qv = *(const float4*)(W + (size_t)idx * DIM + c4 * 4);
    float4 t, o;
    t.x = qv.x - zv.x; t.y = qv.y - zv.y; t.z = qv.z - zv.z; t.w = qv.w - zv.w;
    o.x = zv.x + t.x;  o.y = zv.y + t.y;  o.z = zv.z + t.z;  o.w = zv.w + t.w;
    *(float4*)(out + (size_t)row * DIM + c4 * 4) = o;
    lsum += t.x * t.x + t.y * t.y + t.z * t.z + t.w * t.w;
  }
#pragma unroll
  for (int m = 1; m < 64; m <<= 1) lsum += __shfl_xor(lsum, m, 64);
  __shared__ float part[4];
  if ((tid & 63) == 0) part[tid >> 6] = lsum;
  __syncthreads();
  if (tid == 0) atomicAdd(&ws[WS_LOSS], (part[0] + part[1]) + (part[2] + part[3]));
}

__global__ void finalize_kernel(const float* __restrict__ ws, float* __restrict__ out) {
  if (threadIdx.x == 0 && blockIdx.x == 0) {
    const float mean = ws[WS_LOSS] / (float)(N_ROWS * DIM);
    out[LOSS_OFF] = mean + 0.25f * mean;
  }
}

extern "C" void kernel_launch(void* const* d_in, const int* in_sizes, int n_in,
                              void* d_out, int out_size, void* d_ws, size_t ws_size,
                              hipStream_t stream) {
  (void)in_sizes; (void)n_in; (void)out_size; (void)ws_size;
  const float* z = (const float*)d_in[0];
  const float* W = (const float*)d_in[1];
  float* out = (float*)d_out;
  float* ws = (float*)d_ws;
  unsigned short* outu = (unsigned short*)d_out;
  const unsigned short* wbf = outu + OUT_WBF_U16;
  const unsigned short* zbf = outu + OUT_ZBF_U16;
  uint2* candp = (uint2*)((float*)d_out + OUT_CAND_F);

  hipLaunchKernelGGL(prep_kernel, dim3((N_ROWS + K_CODES) / 16), dim3(256), 0, stream,
                     z, W, ws, outu);
  hipLaunchKernelGGL(gemm_screen_kernel, dim3(K_CODES / 128, N_ROWS / 128), dim3(256),
                     0, stream, zbf, wbf, ws, candp);
  hipLaunchKernelGGL(recheck_kernel, dim3(N_ROWS / 4), dim3(256), 0, stream,
                     z, W, ws, candp, out);
  hipLaunchKernelGGL(fallback_compute, dim3(2048), dim3(256), 0, stream, z, W, ws);
  hipLaunchKernelGGL(gather_loss_kernel, dim3(N_ROWS / 64), dim3(256), 0, stream,
                     z, W, out, ws);
  hipLaunchKernelGGL(finalize_kernel, dim3(1), dim3(64), 0, stream, ws, out);
}